// Round 8
// baseline (1487.060 us; speedup 1.0000x reference)
//
#include <hip/hip_runtime.h>

typedef unsigned int uint;
typedef unsigned short ushort;
typedef __attribute__((ext_vector_type(8))) short short8v;  // 8 bf16 bit patterns
typedef __attribute__((ext_vector_type(4))) float f32x4;

#define IN_DIM 256
#define HID 128
#define BN_EPS 1e-5f
#define NSHARD 8

__device__ __forceinline__ float bf2f(ushort u) { return __uint_as_float(((uint)u) << 16); }
__device__ __forceinline__ ushort f2bf(float f) {
    uint u = __float_as_uint(f);
    return (ushort)((u + 0x7fffu + ((u >> 16) & 1u)) >> 16);  // RNE
}
// HW packed convert, RNE — 1 op for 2 floats (lo = a, hi = b)
__device__ __forceinline__ uint cvt_pk_bf16(float a, float b) {
    uint r;
    asm("v_cvt_pk_bf16_f32 %0, %1, %2" : "=v"(r) : "v"(a), "v"(b));
    return r;
}

// ---------------- CSR build ----------------

__global__ void count_deg_kernel(const int* __restrict__ ei, int* __restrict__ deg, int E) {
    int e = blockIdx.x * blockDim.x + threadIdx.x;
    if (e < E) atomicAdd(&deg[ei[E + e]], 1);
}

#define SCAN_THREADS 256
#define SCAN_ELEMS 1024

__global__ __launch_bounds__(SCAN_THREADS) void scan1_kernel(const int* __restrict__ deg,
                                                             int* __restrict__ outp,
                                                             int* __restrict__ bsum, int n) {
    __shared__ int sdata[SCAN_THREADS];
    int t = threadIdx.x;
    int base = blockIdx.x * SCAN_ELEMS + t * 4;
    int v0 = 0, v1 = 0, v2 = 0, v3 = 0;
    if (base + 0 < n) v0 = deg[base + 0];
    if (base + 1 < n) v1 = deg[base + 1];
    if (base + 2 < n) v2 = deg[base + 2];
    if (base + 3 < n) v3 = deg[base + 3];
    int s = v0 + v1 + v2 + v3;
    sdata[t] = s;
    __syncthreads();
    int val = s;
    for (int off = 1; off < SCAN_THREADS; off <<= 1) {
        int add = (t >= off) ? sdata[t - off] : 0;
        __syncthreads();
        val += add;
        sdata[t] = val;
        __syncthreads();
    }
    int excl = val - s;
    if (base + 0 < n) outp[base + 0] = excl;
    if (base + 1 < n) outp[base + 1] = excl + v0;
    if (base + 2 < n) outp[base + 2] = excl + v0 + v1;
    if (base + 3 < n) outp[base + 3] = excl + v0 + v1 + v2;
    if (t == SCAN_THREADS - 1) bsum[blockIdx.x] = val;
}

__global__ void scan2_kernel(int* bsum, int nb) {
    if (threadIdx.x == 0 && blockIdx.x == 0) {
        int acc = 0;
        for (int i = 0; i < nb; i++) { int v = bsum[i]; bsum[i] = acc; acc += v; }
        bsum[nb] = acc;
    }
}

__global__ void scan3_kernel(int* __restrict__ row_ptr, const int* __restrict__ bsum, int n, int nb) {
    int i = blockIdx.x * blockDim.x + threadIdx.x;
    if (i < n) row_ptr[i] += bsum[i >> 10];
    else if (i == n) row_ptr[n] = bsum[nb];
}

// XCD-sharded CSR fill (round-5 WIN: write locality per XCD L2).
__global__ __launch_bounds__(256) void fill_csr_sharded(const int* __restrict__ ei,
                                                        int* __restrict__ cursor,
                                                        int* __restrict__ esrc,
                                                        int E, int shardSize) {
    int s = blockIdx.x & (NSHARD - 1);
    int rank = blockIdx.x >> 3;
    int nteam = gridDim.x >> 3;
    int lo = s * shardSize;
    int hi = lo + shardSize;
    int stride = nteam * blockDim.x;
    for (int e = rank * blockDim.x + threadIdx.x; e < E; e += stride) {
        int d = ei[E + e];
        if (d >= lo && d < hi) {
            int pos = atomicAdd(&cursor[d], 1);
            esrc[pos] = ei[e];
        }
    }
}

// ---------------- Weight pre-pack: fp32 [k][c] -> bf16 [c][k] (frag-ready) ----------------

__global__ __launch_bounds__(256) void pack_win(const float* __restrict__ W, ushort* __restrict__ Wt) {
    int idx = blockIdx.x * 256 + threadIdx.x;   // 256*128 = 32768 threads
    int k = idx >> 7, c = idx & 127;
    Wt[c * IN_DIM + k] = f2bf(W[idx]);          // W[k*128+c] == W[idx]
}

// WcatT[layer][c][k]: k<128 from Wl, k>=128 from Wr (concat-K layout)
__global__ __launch_bounds__(256) void pack_wcat(const float* __restrict__ Wl,
                                                 const float* __restrict__ Wr,
                                                 ushort* __restrict__ Wt) {
    int idx = blockIdx.x * 256 + threadIdx.x;   // 4*256*128 = 131072 threads
    int layer = idx >> 15;
    int rem = idx & 32767;
    int k = rem >> 7, c = rem & 127;
    float v = (k < HID) ? Wl[layer * HID * HID + k * HID + c]
                        : Wr[layer * HID * HID + (k - HID) * HID + c];
    Wt[layer * (HID * 256) + c * 256 + k] = f2bf(v);
}

// ---------------- Column-sharded aggregation (round-8) ----------------
// shard = blockIdx&7 rides the XCD round-robin (validated round 5): each XCD
// gathers only a 16-col slice of h (3.2MB -> fits its 4MB L2), turning the
// 410MB random-row gather into L2 hits. 8 lanes/edge x 4B (2 cols/lane),
// 16 edges in flight; butterfly-reduce over the 8 edge-groups; write
// meanT[c][node] (sequential 2B per col-row, single-XCD -> L2 write-merge).
__global__ __launch_bounds__(256) void sage_mean_sharded(const ushort* __restrict__ h,
                                                         const int* __restrict__ row_ptr,
                                                         const int* __restrict__ esrc,
                                                         ushort* __restrict__ meanT, int n) {
    int shard = blockIdx.x & (NSHARD - 1);
    int node = (blockIdx.x >> 3) * 4 + (threadIdx.x >> 6);
    if (node >= n) return;
    int lane = threadIdx.x & 63;
    int e_sub = lane >> 3;          // 0..7 : edge slot
    int c_off = lane & 7;           // 0..7 : col pair within slice
    int col0 = shard * 16 + c_off * 2;
    const ushort* hc = h + col0;
    int start = row_ptr[node];
    int end = row_ptr[node + 1];
    float ax = 0.f, ay = 0.f;
    int jb = start;
    for (; jb + 16 <= end; jb += 16) {
        int s0 = esrc[jb + e_sub];
        int s1 = esrc[jb + 8 + e_sub];
        uint v0 = *(const uint*)(hc + (size_t)s0 * HID);
        uint v1 = *(const uint*)(hc + (size_t)s1 * HID);
        ax += bf2f((ushort)(v0 & 0xffffu)) + bf2f((ushort)(v1 & 0xffffu));
        ay += bf2f((ushort)(v0 >> 16)) + bf2f((ushort)(v1 >> 16));
    }
    for (; jb + 8 <= end; jb += 8) {
        int s0 = esrc[jb + e_sub];
        uint v0 = *(const uint*)(hc + (size_t)s0 * HID);
        ax += bf2f((ushort)(v0 & 0xffffu));
        ay += bf2f((ushort)(v0 >> 16));
    }
    if (e_sub < end - jb) {
        int s0 = esrc[jb + e_sub];
        uint v0 = *(const uint*)(hc + (size_t)s0 * HID);
        ax += bf2f((ushort)(v0 & 0xffffu));
        ay += bf2f((ushort)(v0 >> 16));
    }
    #pragma unroll
    for (int off = 8; off < 64; off <<= 1) {
        ax += __shfl_xor(ax, off);
        ay += __shfl_xor(ay, off);
    }
    if (lane < 8) {
        int deg = end - start;
        float inv = 1.0f / (float)(deg > 1 ? deg : 1);
        meanT[(size_t)col0 * n + node] = f2bf(ax * inv);
        meanT[(size_t)(col0 + 1) * n + node] = f2bf(ay * inv);
    }
}

// meanT[c][node] -> meanb[node][c], 64-node tiles via LDS (pad +2: conflict-free)
__global__ __launch_bounds__(256) void transpose_mean(const ushort* __restrict__ meanT,
                                                      ushort* __restrict__ meanb, int n) {
    __shared__ ushort tile[64][HID + 2];
    int node0 = blockIdx.x * 64;
    int t = threadIdx.x;
    #pragma unroll
    for (int i = 0; i < 32; i++) {
        int idx = t + i * 256;
        int no = idx & 63;
        int c = idx >> 6;
        int node = node0 + no;
        ushort v = 0;
        if (node < n) v = meanT[(size_t)c * n + node];
        tile[no][c] = v;
    }
    __syncthreads();
    #pragma unroll
    for (int i = 0; i < 32; i++) {
        int idx = t + i * 256;
        int c = idx & 127;
        int no = idx >> 7;
        int node = node0 + no;
        if (node < n) meanb[(size_t)node * HID + c] = tile[no][c];
    }
}

// ---------------- Input GEMM: h = relu(x @ W_in + b_in), MFMA ----------------
// B-frags: single 16B loads from packed bf16 Wt_in[c][k] (no per-block
// convert prologue). A: fp32 loads + v_cvt_pk_bf16_f32 (1 op / 2 elems vs
// ~5 ops/elem round-7 emulation). Natural regalloc (round-6 lesson).

__global__ __launch_bounds__(256) void input_gemm_mfma(const float* __restrict__ x,
                                                       const ushort* __restrict__ Wt,
                                                       const float* __restrict__ b,
                                                       ushort* __restrict__ hout, int n) {
    int t = threadIdx.x;
    int l = t & 63;
    int wv = t >> 6;
    int colbase = wv * 32;
    int lr = l & 15;
    int grp = l >> 4;
    int ko = grp * 8;

    short8v Bf[8][2];
    #pragma unroll
    for (int ks = 0; ks < 8; ks++) {
        #pragma unroll
        for (int nt = 0; nt < 2; nt++) {
            int c = colbase + nt * 16 + lr;
            Bf[ks][nt] = *(const short8v*)(Wt + (size_t)c * IN_DIM + ks * 32 + ko);
        }
    }
    float bias0 = b[colbase + lr];
    float bias1 = b[colbase + 16 + lr];

    int ntiles = (n + 15) >> 4;
    for (int tile = blockIdx.x; tile < ntiles; tile += gridDim.x) {
        int row0 = tile * 16;
        int arow = row0 + lr;
        const float* xr = x + (size_t)arow * IN_DIM + ko;
        short8v Af[8];
        if (arow < n) {
            #pragma unroll
            for (int ks = 0; ks < 8; ks++) {
                float4 p = *(const float4*)(xr + ks * 32);
                float4 q = *(const float4*)(xr + ks * 32 + 4);
                union { uint4 u; short8v s; } cv;
                cv.u.x = cvt_pk_bf16(p.x, p.y);
                cv.u.y = cvt_pk_bf16(p.z, p.w);
                cv.u.z = cvt_pk_bf16(q.x, q.y);
                cv.u.w = cvt_pk_bf16(q.z, q.w);
                Af[ks] = cv.s;
            }
        } else {
            #pragma unroll
            for (int ks = 0; ks < 8; ks++) {
                short8v a = {0, 0, 0, 0, 0, 0, 0, 0};
                Af[ks] = a;
            }
        }
        f32x4 acc0 = {0.f, 0.f, 0.f, 0.f};
        f32x4 acc1 = {0.f, 0.f, 0.f, 0.f};
        #pragma unroll
        for (int ks = 0; ks < 8; ks++) {
            acc0 = __builtin_amdgcn_mfma_f32_16x16x32_bf16(Af[ks], Bf[ks][0], acc0, 0, 0, 0);
            acc1 = __builtin_amdgcn_mfma_f32_16x16x32_bf16(Af[ks], Bf[ks][1], acc1, 0, 0, 0);
        }
        int rbase = row0 + grp * 4;
        #pragma unroll
        for (int r = 0; r < 4; r++) {
            int rowd = rbase + r;
            if (rowd < n) {
                float z0 = acc0[r] + bias0; z0 = z0 > 0.f ? z0 : 0.f;
                float z1 = acc1[r] + bias1; z1 = z1 > 0.f ? z1 : 0.f;
                hout[(size_t)rowd * HID + colbase + lr] = f2bf(z0);
                hout[(size_t)rowd * HID + colbase + 16 + lr] = f2bf(z1);
            }
        }
    }
}

// ---------------- Fused SAGE layer, MFMA ----------------
// B-frags from packed WcatT (16B loads, no convert prologue).

__global__ __launch_bounds__(256) void sage_layer_mfma(const ushort* __restrict__ h,
                                                       const ushort* __restrict__ mh,
                                                       ushort* __restrict__ hout,
                                                       const ushort* __restrict__ Wt,
                                                       const float* __restrict__ bl,
                                                       const float* __restrict__ br,
                                                       const float* __restrict__ gamma,
                                                       const float* __restrict__ beta,
                                                       const float* __restrict__ bmean,
                                                       const float* __restrict__ bvar,
                                                       int n) {
    int t = threadIdx.x;
    int l = t & 63;
    int wv = t >> 6;
    int colbase = wv * 32;
    int lr = l & 15;
    int grp = l >> 4;
    int ko = grp * 8;

    short8v Bf[8][2];
    #pragma unroll
    for (int ks = 0; ks < 8; ks++) {
        #pragma unroll
        for (int nt = 0; nt < 2; nt++) {
            int c = colbase + nt * 16 + lr;
            Bf[ks][nt] = *(const short8v*)(Wt + (size_t)c * 256 + ks * 32 + ko);
        }
    }
    int c0 = colbase + lr;
    int c1 = c0 + 16;
    float scale0 = gamma[c0] * rsqrtf(bvar[c0] + BN_EPS);
    float scale1 = gamma[c1] * rsqrtf(bvar[c1] + BN_EPS);
    float shift0 = beta[c0] + (bl[c0] + br[c0] - bmean[c0]) * scale0;
    float shift1 = beta[c1] + (bl[c1] + br[c1] - bmean[c1]) * scale1;

    int ntiles = (n + 15) >> 4;
    for (int tile = blockIdx.x; tile < ntiles; tile += gridDim.x) {
        int row0 = tile * 16;
        int arow = row0 + lr;
        short8v Af[8];
        if (arow < n) {
            const ushort* mrow = mh + (size_t)arow * HID + ko;
            const ushort* hrow = h + (size_t)arow * HID + ko;
            #pragma unroll
            for (int ks = 0; ks < 4; ks++) Af[ks] = *(const short8v*)(mrow + ks * 32);
            #pragma unroll
            for (int ks = 4; ks < 8; ks++) Af[ks] = *(const short8v*)(hrow + (ks - 4) * 32);
        } else {
            #pragma unroll
            for (int ks = 0; ks < 8; ks++) {
                short8v a = {0, 0, 0, 0, 0, 0, 0, 0};
                Af[ks] = a;
            }
        }
        f32x4 acc0 = {0.f, 0.f, 0.f, 0.f};
        f32x4 acc1 = {0.f, 0.f, 0.f, 0.f};
        #pragma unroll
        for (int ks = 0; ks < 8; ks++) {
            acc0 = __builtin_amdgcn_mfma_f32_16x16x32_bf16(Af[ks], Bf[ks][0], acc0, 0, 0, 0);
            acc1 = __builtin_amdgcn_mfma_f32_16x16x32_bf16(Af[ks], Bf[ks][1], acc1, 0, 0, 0);
        }
        int rbase = row0 + grp * 4;
        #pragma unroll
        for (int r = 0; r < 4; r++) {
            int rowd = rbase + r;
            if (rowd < n) {
                float z0 = acc0[r] * scale0 + shift0; z0 = z0 > 0.f ? z0 : 0.f;
                float z1 = acc1[r] * scale1 + shift1; z1 = z1 > 0.f ? z1 : 0.f;
                z0 += bf2f(h[(size_t)rowd * HID + c0]);
                z1 += bf2f(h[(size_t)rowd * HID + c1]);
                hout[(size_t)rowd * HID + c0] = f2bf(z0);
                hout[(size_t)rowd * HID + c1] = f2bf(z1);
            }
        }
    }
}

// ---------------- Classifier + log_softmax (bf16 h) ----------------

__global__ __launch_bounds__(256) void classifier_bf16(const ushort* __restrict__ h,
                                                       const float* __restrict__ Wc,
                                                       const float* __restrict__ bc,
                                                       float* __restrict__ outp, int n) {
    __shared__ float Wcs[HID * 2];
    int t = threadIdx.x;
    if (t < 64) *(float4*)&Wcs[t * 4] = *(const float4*)&Wc[t * 4];
    __syncthreads();
    int rowInBlk = t >> 4;
    int sub = t & 15;
    int row = blockIdx.x * 16 + rowInBlk;
    float l0 = 0.f, l1 = 0.f;
    if (row < n) {
        const ushort* hr = h + (size_t)row * HID + sub * 8;
        uint4 v = *(const uint4*)hr;
        float e0 = bf2f((ushort)(v.x & 0xffffu)), e1 = bf2f((ushort)(v.x >> 16));
        float e2 = bf2f((ushort)(v.y & 0xffffu)), e3 = bf2f((ushort)(v.y >> 16));
        float e4 = bf2f((ushort)(v.z & 0xffffu)), e5 = bf2f((ushort)(v.z >> 16));
        float e6 = bf2f((ushort)(v.w & 0xffffu)), e7 = bf2f((ushort)(v.w >> 16));
        int k0 = sub * 8;
        l0 += e0 * Wcs[(k0 + 0) * 2] + e1 * Wcs[(k0 + 1) * 2] + e2 * Wcs[(k0 + 2) * 2] + e3 * Wcs[(k0 + 3) * 2];
        l0 += e4 * Wcs[(k0 + 4) * 2] + e5 * Wcs[(k0 + 5) * 2] + e6 * Wcs[(k0 + 6) * 2] + e7 * Wcs[(k0 + 7) * 2];
        l1 += e0 * Wcs[(k0 + 0) * 2 + 1] + e1 * Wcs[(k0 + 1) * 2 + 1] + e2 * Wcs[(k0 + 2) * 2 + 1] + e3 * Wcs[(k0 + 3) * 2 + 1];
        l1 += e4 * Wcs[(k0 + 4) * 2 + 1] + e5 * Wcs[(k0 + 5) * 2 + 1] + e6 * Wcs[(k0 + 6) * 2 + 1] + e7 * Wcs[(k0 + 7) * 2 + 1];
    }
    #pragma unroll
    for (int off = 1; off < 16; off <<= 1) {
        l0 += __shfl_xor(l0, off);
        l1 += __shfl_xor(l1, off);
    }
    if (sub == 0 && row < n) {
        l0 += bc[0];
        l1 += bc[1];
        float m = fmaxf(l0, l1);
        float lse = m + logf(expf(l0 - m) + expf(l1 - m));
        outp[(size_t)row * 2 + 0] = l0 - lse;
        outp[(size_t)row * 2 + 1] = l1 - lse;
    }
}

// ---------------- host ----------------

extern "C" void kernel_launch(void* const* d_in, const int* in_sizes, int n_in,
                              void* d_out, int out_size, void* d_ws, size_t ws_size,
                              hipStream_t stream) {
    const float* x     = (const float*)d_in[0];
    const int*   ei    = (const int*)d_in[1];
    const float* W_in  = (const float*)d_in[2];
    const float* b_in  = (const float*)d_in[3];
    const float* W_l   = (const float*)d_in[4];
    const float* b_l   = (const float*)d_in[5];
    const float* W_r   = (const float*)d_in[6];
    const float* b_r   = (const float*)d_in[7];
    const float* bn_g  = (const float*)d_in[8];
    const float* bn_b  = (const float*)d_in[9];
    const float* bn_m  = (const float*)d_in[10];
    const float* bn_v  = (const float*)d_in[11];
    const float* W_cls = (const float*)d_in[12];
    const float* b_cls = (const float*)d_in[13];
    float* outp = (float*)d_out;

    const int N = in_sizes[0] / IN_DIM;   // 100000
    const int E = in_sizes[1] / 2;        // 1600000

    char* w = (char*)d_ws;
    const size_t HB = (size_t)N * HID * sizeof(ushort);          // 25.6 MB per buffer
    ushort* hA     = (ushort*)(w);
    ushort* hB     = (ushort*)(w + HB);
    ushort* meanb  = (ushort*)(w + 2 * HB);
    ushort* meanT  = (ushort*)(w + 3 * HB);                      // [128][N]
    ushort* Wt_in  = (ushort*)(w + 4 * HB);                      // 64 KB
    ushort* WcatT  = (ushort*)(w + 4 * HB + 65536);              // 256 KB
    char*  ints    = w + 4 * HB + 65536 + 262144;
    int*   row_ptr = (int*)(ints);                               // N+1 ints
    int*   cursor  = (int*)(ints + 400128);
    int*   bsum    = (int*)(ints + 800256);
    int*   esrc    = (int*)(ints + 801280);                      // E ints

    const int nbScan = (N + SCAN_ELEMS - 1) / SCAN_ELEMS;
    const int shardSize = (N + NSHARD - 1) / NSHARD;             // 12500

    // --- weight pre-pack (bf16, frag-ready [c][k]) ---
    pack_win<<<128, 256, 0, stream>>>(W_in, Wt_in);
    pack_wcat<<<512, 256, 0, stream>>>(W_l, W_r, WcatT);

    // --- CSR build ---
    hipMemsetAsync(cursor, 0, (size_t)N * sizeof(int), stream);
    count_deg_kernel<<<(E + 255) / 256, 256, 0, stream>>>(ei, cursor, E);
    scan1_kernel<<<nbScan, SCAN_THREADS, 0, stream>>>(cursor, row_ptr, bsum, N);
    scan2_kernel<<<1, 64, 0, stream>>>(bsum, nbScan);
    scan3_kernel<<<(N + 256) / 256, 256, 0, stream>>>(row_ptr, bsum, N, nbScan);
    hipMemcpyAsync(cursor, row_ptr, (size_t)N * sizeof(int), hipMemcpyDeviceToDevice, stream);
    fill_csr_sharded<<<2048, 256, 0, stream>>>(ei, cursor, esrc, E, shardSize);

    // --- input projection (fp32 x -> bf16 h via cvt_pk + packed B) ---
    input_gemm_mfma<<<3125, 256, 0, stream>>>(x, Wt_in, b_in, hA, N);

    // --- 4 SAGE layers ---
    ushort* hcur = hA;
    ushort* hoth = hB;
    const int aggGrid = ((N + 3) / 4) * NSHARD;                  // 200000
    for (int i = 0; i < 4; i++) {
        sage_mean_sharded<<<aggGrid, 256, 0, stream>>>(hcur, row_ptr, esrc, meanT, N);
        transpose_mean<<<(N + 63) / 64, 256, 0, stream>>>(meanT, meanb, N);
        sage_layer_mfma<<<3125, 256, 0, stream>>>(hcur, meanb, hoth,
                                                  WcatT + (size_t)i * HID * 256,
                                                  b_l + i * HID, b_r + i * HID,
                                                  bn_g + i * HID, bn_b + i * HID,
                                                  bn_m + i * HID, bn_v + i * HID, N);
        ushort* tmp = hcur; hcur = hoth; hoth = tmp;
    }

    // --- classifier + log_softmax ---
    classifier_bf16<<<(N + 15) / 16, 256, 0, stream>>>(hcur, W_cls, b_cls, outp, N);
}

// Round 9
// 749.430 us; speedup vs baseline: 1.9843x; 1.9843x over previous
//
#include <hip/hip_runtime.h>

typedef unsigned int uint;
typedef unsigned short ushort;
typedef __attribute__((ext_vector_type(8))) short short8v;  // 8 bf16 bit patterns
typedef __attribute__((ext_vector_type(4))) float f32x4;

#define IN_DIM 256
#define HID 128
#define BN_EPS 1e-5f
#define NSHARD 8

__device__ __forceinline__ float bf2f(ushort u) { return __uint_as_float(((uint)u) << 16); }
__device__ __forceinline__ ushort f2bf(float f) {
    uint u = __float_as_uint(f);
    return (ushort)((u + 0x7fffu + ((u >> 16) & 1u)) >> 16);  // RNE
}
// HW packed convert, RNE — 1 op for 2 floats (lo = a, hi = b)
__device__ __forceinline__ uint cvt_pk_bf16(float a, float b) {
    uint r;
    asm("v_cvt_pk_bf16_f32 %0, %1, %2" : "=v"(r) : "v"(a), "v"(b));
    return r;
}

// ---------------- CSR build ----------------

// XCD-sharded degree count (round-5 pattern): each shard's 50KB deg slice
// stays in ONE XCD's L2 -> atomics localized, no cross-XCD line ping-pong.
__global__ __launch_bounds__(256) void count_deg_sharded(const int* __restrict__ ei,
                                                         int* __restrict__ deg,
                                                         int E, int shardSize) {
    int s = blockIdx.x & (NSHARD - 1);
    int rank = blockIdx.x >> 3;
    int nteam = gridDim.x >> 3;
    int lo = s * shardSize;
    int hi = lo + shardSize;
    int stride = nteam * blockDim.x;
    for (int e = rank * blockDim.x + threadIdx.x; e < E; e += stride) {
        int d = ei[E + e];
        if (d >= lo && d < hi) atomicAdd(&deg[d], 1);
    }
}

#define SCAN_THREADS 256
#define SCAN_ELEMS 1024

__global__ __launch_bounds__(SCAN_THREADS) void scan1_kernel(const int* __restrict__ deg,
                                                             int* __restrict__ outp,
                                                             int* __restrict__ bsum, int n) {
    __shared__ int sdata[SCAN_THREADS];
    int t = threadIdx.x;
    int base = blockIdx.x * SCAN_ELEMS + t * 4;
    int v0 = 0, v1 = 0, v2 = 0, v3 = 0;
    if (base + 0 < n) v0 = deg[base + 0];
    if (base + 1 < n) v1 = deg[base + 1];
    if (base + 2 < n) v2 = deg[base + 2];
    if (base + 3 < n) v3 = deg[base + 3];
    int s = v0 + v1 + v2 + v3;
    sdata[t] = s;
    __syncthreads();
    int val = s;
    for (int off = 1; off < SCAN_THREADS; off <<= 1) {
        int add = (t >= off) ? sdata[t - off] : 0;
        __syncthreads();
        val += add;
        sdata[t] = val;
        __syncthreads();
    }
    int excl = val - s;
    if (base + 0 < n) outp[base + 0] = excl;
    if (base + 1 < n) outp[base + 1] = excl + v0;
    if (base + 2 < n) outp[base + 2] = excl + v0 + v1;
    if (base + 3 < n) outp[base + 3] = excl + v0 + v1 + v2;
    if (t == SCAN_THREADS - 1) bsum[blockIdx.x] = val;
}

__global__ void scan2_kernel(int* bsum, int nb) {
    if (threadIdx.x == 0 && blockIdx.x == 0) {
        int acc = 0;
        for (int i = 0; i < nb; i++) { int v = bsum[i]; bsum[i] = acc; acc += v; }
        bsum[nb] = acc;
    }
}

__global__ void scan3_kernel(int* __restrict__ row_ptr, const int* __restrict__ bsum, int n, int nb) {
    int i = blockIdx.x * blockDim.x + threadIdx.x;
    if (i < n) row_ptr[i] += bsum[i >> 10];
    else if (i == n) row_ptr[n] = bsum[nb];
}

// XCD-sharded CSR fill (round-5 WIN: write locality per XCD L2).
__global__ __launch_bounds__(256) void fill_csr_sharded(const int* __restrict__ ei,
                                                        int* __restrict__ cursor,
                                                        int* __restrict__ esrc,
                                                        int E, int shardSize) {
    int s = blockIdx.x & (NSHARD - 1);
    int rank = blockIdx.x >> 3;
    int nteam = gridDim.x >> 3;
    int lo = s * shardSize;
    int hi = lo + shardSize;
    int stride = nteam * blockDim.x;
    for (int e = rank * blockDim.x + threadIdx.x; e < E; e += stride) {
        int d = ei[E + e];
        if (d >= lo && d < hi) {
            int pos = atomicAdd(&cursor[d], 1);
            esrc[pos] = ei[e];
        }
    }
}

// ---------------- Weight pre-pack: fp32 [k][c] -> bf16 [c][k] (frag-ready) ----------------

__global__ __launch_bounds__(256) void pack_win(const float* __restrict__ W, ushort* __restrict__ Wt) {
    int idx = blockIdx.x * 256 + threadIdx.x;   // 256*128 = 32768 threads
    int k = idx >> 7, c = idx & 127;
    Wt[c * IN_DIM + k] = f2bf(W[idx]);          // W[k*128+c] == W[idx]
}

// WcatT[layer][c][k]: k<128 from Wl, k>=128 from Wr (concat-K layout)
__global__ __launch_bounds__(256) void pack_wcat(const float* __restrict__ Wl,
                                                 const float* __restrict__ Wr,
                                                 ushort* __restrict__ Wt) {
    int idx = blockIdx.x * 256 + threadIdx.x;   // 4*256*128 = 131072 threads
    int layer = idx >> 15;
    int rem = idx & 32767;
    int k = rem >> 7, c = rem & 127;
    float v = (k < HID) ? Wl[layer * HID * HID + k * HID + c]
                        : Wr[layer * HID * HID + (k - HID) * HID + c];
    Wt[layer * (HID * 256) + c * 256 + k] = f2bf(v);
}

// ---------------- Aggregation: mean over in-neighbors (bf16 rows) ----------------
// ROW-gather (round-8 column-sharding refuted: strided 32B slices have a
// line-granular L2 footprint of 6.4-12.8MB/XCD > 4MB -> thrash -> 583MB HBM).
// Full 256B row reads are line-aligned out of the L3-resident h (25.6MB);
// one wave per node, lane owns 2 cols, 8 edges in flight.

__global__ __launch_bounds__(256) void sage_mean_bf16(const ushort* __restrict__ h,
                                                      const int* __restrict__ row_ptr,
                                                      const int* __restrict__ esrc,
                                                      ushort* __restrict__ meanb, int n) {
    int node = blockIdx.x * 4 + (threadIdx.x >> 6);
    if (node >= n) return;
    int lane = threadIdx.x & 63;
    int start = row_ptr[node];
    int end = row_ptr[node + 1];
    float ax = 0.f, ay = 0.f;
    int j = start;
    for (; j + 7 < end; j += 8) {
        uint v0 = *(const uint*)(h + (size_t)esrc[j + 0] * HID + lane * 2);
        uint v1 = *(const uint*)(h + (size_t)esrc[j + 1] * HID + lane * 2);
        uint v2 = *(const uint*)(h + (size_t)esrc[j + 2] * HID + lane * 2);
        uint v3 = *(const uint*)(h + (size_t)esrc[j + 3] * HID + lane * 2);
        uint v4 = *(const uint*)(h + (size_t)esrc[j + 4] * HID + lane * 2);
        uint v5 = *(const uint*)(h + (size_t)esrc[j + 5] * HID + lane * 2);
        uint v6 = *(const uint*)(h + (size_t)esrc[j + 6] * HID + lane * 2);
        uint v7 = *(const uint*)(h + (size_t)esrc[j + 7] * HID + lane * 2);
        ax += bf2f((ushort)(v0 & 0xffffu)) + bf2f((ushort)(v1 & 0xffffu))
            + bf2f((ushort)(v2 & 0xffffu)) + bf2f((ushort)(v3 & 0xffffu))
            + bf2f((ushort)(v4 & 0xffffu)) + bf2f((ushort)(v5 & 0xffffu))
            + bf2f((ushort)(v6 & 0xffffu)) + bf2f((ushort)(v7 & 0xffffu));
        ay += bf2f((ushort)(v0 >> 16)) + bf2f((ushort)(v1 >> 16))
            + bf2f((ushort)(v2 >> 16)) + bf2f((ushort)(v3 >> 16))
            + bf2f((ushort)(v4 >> 16)) + bf2f((ushort)(v5 >> 16))
            + bf2f((ushort)(v6 >> 16)) + bf2f((ushort)(v7 >> 16));
    }
    for (; j < end; ++j) {
        uint v0 = *(const uint*)(h + (size_t)esrc[j] * HID + lane * 2);
        ax += bf2f((ushort)(v0 & 0xffffu));
        ay += bf2f((ushort)(v0 >> 16));
    }
    int deg = end - start;
    float inv = 1.0f / (float)(deg > 1 ? deg : 1);
    uint o = (uint)f2bf(ax * inv) | (((uint)f2bf(ay * inv)) << 16);
    *(uint*)(meanb + (size_t)node * HID + lane * 2) = o;
}

// ---------------- Input GEMM: h = relu(x @ W_in + b_in), MFMA ----------------
// B-frags: single 16B loads from packed bf16 Wt_in[c][k]; A via cvt_pk.
// Natural regalloc (round-6 spill lesson).

__global__ __launch_bounds__(256) void input_gemm_mfma(const float* __restrict__ x,
                                                       const ushort* __restrict__ Wt,
                                                       const float* __restrict__ b,
                                                       ushort* __restrict__ hout, int n) {
    int t = threadIdx.x;
    int l = t & 63;
    int wv = t >> 6;
    int colbase = wv * 32;
    int lr = l & 15;
    int grp = l >> 4;
    int ko = grp * 8;

    short8v Bf[8][2];
    #pragma unroll
    for (int ks = 0; ks < 8; ks++) {
        #pragma unroll
        for (int nt = 0; nt < 2; nt++) {
            int c = colbase + nt * 16 + lr;
            Bf[ks][nt] = *(const short8v*)(Wt + (size_t)c * IN_DIM + ks * 32 + ko);
        }
    }
    float bias0 = b[colbase + lr];
    float bias1 = b[colbase + 16 + lr];

    int ntiles = (n + 15) >> 4;
    for (int tile = blockIdx.x; tile < ntiles; tile += gridDim.x) {
        int row0 = tile * 16;
        int arow = row0 + lr;
        const float* xr = x + (size_t)arow * IN_DIM + ko;
        short8v Af[8];
        if (arow < n) {
            #pragma unroll
            for (int ks = 0; ks < 8; ks++) {
                float4 p = *(const float4*)(xr + ks * 32);
                float4 q = *(const float4*)(xr + ks * 32 + 4);
                union { uint4 u; short8v s; } cv;
                cv.u.x = cvt_pk_bf16(p.x, p.y);
                cv.u.y = cvt_pk_bf16(p.z, p.w);
                cv.u.z = cvt_pk_bf16(q.x, q.y);
                cv.u.w = cvt_pk_bf16(q.z, q.w);
                Af[ks] = cv.s;
            }
        } else {
            #pragma unroll
            for (int ks = 0; ks < 8; ks++) {
                short8v a = {0, 0, 0, 0, 0, 0, 0, 0};
                Af[ks] = a;
            }
        }
        f32x4 acc0 = {0.f, 0.f, 0.f, 0.f};
        f32x4 acc1 = {0.f, 0.f, 0.f, 0.f};
        #pragma unroll
        for (int ks = 0; ks < 8; ks++) {
            acc0 = __builtin_amdgcn_mfma_f32_16x16x32_bf16(Af[ks], Bf[ks][0], acc0, 0, 0, 0);
            acc1 = __builtin_amdgcn_mfma_f32_16x16x32_bf16(Af[ks], Bf[ks][1], acc1, 0, 0, 0);
        }
        int rbase = row0 + grp * 4;
        #pragma unroll
        for (int r = 0; r < 4; r++) {
            int rowd = rbase + r;
            if (rowd < n) {
                float z0 = acc0[r] + bias0; z0 = z0 > 0.f ? z0 : 0.f;
                float z1 = acc1[r] + bias1; z1 = z1 > 0.f ? z1 : 0.f;
                hout[(size_t)rowd * HID + colbase + lr] = f2bf(z0);
                hout[(size_t)rowd * HID + colbase + 16 + lr] = f2bf(z1);
            }
        }
    }
}

// ---------------- Fused SAGE layer, MFMA ----------------
// B-frags from packed WcatT (16B loads). K=256 over concat[mean|h].

__global__ __launch_bounds__(256) void sage_layer_mfma(const ushort* __restrict__ h,
                                                       const ushort* __restrict__ mh,
                                                       ushort* __restrict__ hout,
                                                       const ushort* __restrict__ Wt,
                                                       const float* __restrict__ bl,
                                                       const float* __restrict__ br,
                                                       const float* __restrict__ gamma,
                                                       const float* __restrict__ beta,
                                                       const float* __restrict__ bmean,
                                                       const float* __restrict__ bvar,
                                                       int n) {
    int t = threadIdx.x;
    int l = t & 63;
    int wv = t >> 6;
    int colbase = wv * 32;
    int lr = l & 15;
    int grp = l >> 4;
    int ko = grp * 8;

    short8v Bf[8][2];
    #pragma unroll
    for (int ks = 0; ks < 8; ks++) {
        #pragma unroll
        for (int nt = 0; nt < 2; nt++) {
            int c = colbase + nt * 16 + lr;
            Bf[ks][nt] = *(const short8v*)(Wt + (size_t)c * 256 + ks * 32 + ko);
        }
    }
    int c0 = colbase + lr;
    int c1 = c0 + 16;
    float scale0 = gamma[c0] * rsqrtf(bvar[c0] + BN_EPS);
    float scale1 = gamma[c1] * rsqrtf(bvar[c1] + BN_EPS);
    float shift0 = beta[c0] + (bl[c0] + br[c0] - bmean[c0]) * scale0;
    float shift1 = beta[c1] + (bl[c1] + br[c1] - bmean[c1]) * scale1;

    int ntiles = (n + 15) >> 4;
    for (int tile = blockIdx.x; tile < ntiles; tile += gridDim.x) {
        int row0 = tile * 16;
        int arow = row0 + lr;
        short8v Af[8];
        if (arow < n) {
            const ushort* mrow = mh + (size_t)arow * HID + ko;
            const ushort* hrow = h + (size_t)arow * HID + ko;
            #pragma unroll
            for (int ks = 0; ks < 4; ks++) Af[ks] = *(const short8v*)(mrow + ks * 32);
            #pragma unroll
            for (int ks = 4; ks < 8; ks++) Af[ks] = *(const short8v*)(hrow + (ks - 4) * 32);
        } else {
            #pragma unroll
            for (int ks = 0; ks < 8; ks++) {
                short8v a = {0, 0, 0, 0, 0, 0, 0, 0};
                Af[ks] = a;
            }
        }
        f32x4 acc0 = {0.f, 0.f, 0.f, 0.f};
        f32x4 acc1 = {0.f, 0.f, 0.f, 0.f};
        #pragma unroll
        for (int ks = 0; ks < 8; ks++) {
            acc0 = __builtin_amdgcn_mfma_f32_16x16x32_bf16(Af[ks], Bf[ks][0], acc0, 0, 0, 0);
            acc1 = __builtin_amdgcn_mfma_f32_16x16x32_bf16(Af[ks], Bf[ks][1], acc1, 0, 0, 0);
        }
        int rbase = row0 + grp * 4;
        #pragma unroll
        for (int r = 0; r < 4; r++) {
            int rowd = rbase + r;
            if (rowd < n) {
                float z0 = acc0[r] * scale0 + shift0; z0 = z0 > 0.f ? z0 : 0.f;
                float z1 = acc1[r] * scale1 + shift1; z1 = z1 > 0.f ? z1 : 0.f;
                z0 += bf2f(h[(size_t)rowd * HID + c0]);
                z1 += bf2f(h[(size_t)rowd * HID + c1]);
                hout[(size_t)rowd * HID + c0] = f2bf(z0);
                hout[(size_t)rowd * HID + c1] = f2bf(z1);
            }
        }
    }
}

// ---------------- Classifier + log_softmax (bf16 h) ----------------

__global__ __launch_bounds__(256) void classifier_bf16(const ushort* __restrict__ h,
                                                       const float* __restrict__ Wc,
                                                       const float* __restrict__ bc,
                                                       float* __restrict__ outp, int n) {
    __shared__ float Wcs[HID * 2];
    int t = threadIdx.x;
    if (t < 64) *(float4*)&Wcs[t * 4] = *(const float4*)&Wc[t * 4];
    __syncthreads();
    int rowInBlk = t >> 4;
    int sub = t & 15;
    int row = blockIdx.x * 16 + rowInBlk;
    float l0 = 0.f, l1 = 0.f;
    if (row < n) {
        const ushort* hr = h + (size_t)row * HID + sub * 8;
        uint4 v = *(const uint4*)hr;
        float e0 = bf2f((ushort)(v.x & 0xffffu)), e1 = bf2f((ushort)(v.x >> 16));
        float e2 = bf2f((ushort)(v.y & 0xffffu)), e3 = bf2f((ushort)(v.y >> 16));
        float e4 = bf2f((ushort)(v.z & 0xffffu)), e5 = bf2f((ushort)(v.z >> 16));
        float e6 = bf2f((ushort)(v.w & 0xffffu)), e7 = bf2f((ushort)(v.w >> 16));
        int k0 = sub * 8;
        l0 += e0 * Wcs[(k0 + 0) * 2] + e1 * Wcs[(k0 + 1) * 2] + e2 * Wcs[(k0 + 2) * 2] + e3 * Wcs[(k0 + 3) * 2];
        l0 += e4 * Wcs[(k0 + 4) * 2] + e5 * Wcs[(k0 + 5) * 2] + e6 * Wcs[(k0 + 6) * 2] + e7 * Wcs[(k0 + 7) * 2];
        l1 += e0 * Wcs[(k0 + 0) * 2 + 1] + e1 * Wcs[(k0 + 1) * 2 + 1] + e2 * Wcs[(k0 + 2) * 2 + 1] + e3 * Wcs[(k0 + 3) * 2 + 1];
        l1 += e4 * Wcs[(k0 + 4) * 2 + 1] + e5 * Wcs[(k0 + 5) * 2 + 1] + e6 * Wcs[(k0 + 6) * 2 + 1] + e7 * Wcs[(k0 + 7) * 2 + 1];
    }
    #pragma unroll
    for (int off = 1; off < 16; off <<= 1) {
        l0 += __shfl_xor(l0, off);
        l1 += __shfl_xor(l1, off);
    }
    if (sub == 0 && row < n) {
        l0 += bc[0];
        l1 += bc[1];
        float m = fmaxf(l0, l1);
        float lse = m + logf(expf(l0 - m) + expf(l1 - m));
        outp[(size_t)row * 2 + 0] = l0 - lse;
        outp[(size_t)row * 2 + 1] = l1 - lse;
    }
}

// ---------------- host ----------------

extern "C" void kernel_launch(void* const* d_in, const int* in_sizes, int n_in,
                              void* d_out, int out_size, void* d_ws, size_t ws_size,
                              hipStream_t stream) {
    const float* x     = (const float*)d_in[0];
    const int*   ei    = (const int*)d_in[1];
    const float* W_in  = (const float*)d_in[2];
    const float* b_in  = (const float*)d_in[3];
    const float* W_l   = (const float*)d_in[4];
    const float* b_l   = (const float*)d_in[5];
    const float* W_r   = (const float*)d_in[6];
    const float* b_r   = (const float*)d_in[7];
    const float* bn_g  = (const float*)d_in[8];
    const float* bn_b  = (const float*)d_in[9];
    const float* bn_m  = (const float*)d_in[10];
    const float* bn_v  = (const float*)d_in[11];
    const float* W_cls = (const float*)d_in[12];
    const float* b_cls = (const float*)d_in[13];
    float* outp = (float*)d_out;

    const int N = in_sizes[0] / IN_DIM;   // 100000
    const int E = in_sizes[1] / 2;        // 1600000

    char* w = (char*)d_ws;
    const size_t HB = (size_t)N * HID * sizeof(ushort);          // 25.6 MB per buffer
    ushort* hA     = (ushort*)(w);
    ushort* hB     = (ushort*)(w + HB);
    ushort* meanb  = (ushort*)(w + 2 * HB);
    ushort* Wt_in  = (ushort*)(w + 3 * HB);                      // 64 KB
    ushort* WcatT  = (ushort*)(w + 3 * HB + 65536);              // 256 KB
    char*  ints    = w + 3 * HB + 65536 + 262144;
    int*   row_ptr = (int*)(ints);                               // N+1 ints
    int*   cursor  = (int*)(ints + 400128);
    int*   bsum    = (int*)(ints + 800256);
    int*   esrc    = (int*)(ints + 801280);                      // E ints

    const int nbScan = (N + SCAN_ELEMS - 1) / SCAN_ELEMS;
    const int shardSize = (N + NSHARD - 1) / NSHARD;             // 12500

    // --- weight pre-pack (bf16, frag-ready [c][k]) ---
    pack_win<<<128, 256, 0, stream>>>(W_in, Wt_in);
    pack_wcat<<<512, 256, 0, stream>>>(W_l, W_r, WcatT);

    // --- CSR build ---
    hipMemsetAsync(cursor, 0, (size_t)N * sizeof(int), stream);
    count_deg_sharded<<<2048, 256, 0, stream>>>(ei, cursor, E, shardSize);
    scan1_kernel<<<nbScan, SCAN_THREADS, 0, stream>>>(cursor, row_ptr, bsum, N);
    scan2_kernel<<<1, 64, 0, stream>>>(bsum, nbScan);
    scan3_kernel<<<(N + 256) / 256, 256, 0, stream>>>(row_ptr, bsum, N, nbScan);
    hipMemcpyAsync(cursor, row_ptr, (size_t)N * sizeof(int), hipMemcpyDeviceToDevice, stream);
    fill_csr_sharded<<<2048, 256, 0, stream>>>(ei, cursor, esrc, E, shardSize);

    // --- input projection (fp32 x -> bf16 h via cvt_pk + packed B) ---
    input_gemm_mfma<<<3125, 256, 0, stream>>>(x, Wt_in, b_in, hA, N);

    // --- 4 SAGE layers ---
    ushort* hcur = hA;
    ushort* hoth = hB;
    for (int i = 0; i < 4; i++) {
        sage_mean_bf16<<<(N + 3) / 4, 256, 0, stream>>>(hcur, row_ptr, esrc, meanb, N);
        sage_layer_mfma<<<3125, 256, 0, stream>>>(hcur, meanb, hoth,
                                                  WcatT + (size_t)i * HID * 256,
                                                  b_l + i * HID, b_r + i * HID,
                                                  bn_g + i * HID, bn_b + i * HID,
                                                  bn_m + i * HID, bn_v + i * HID, N);
        ushort* tmp = hcur; hcur = hoth; hoth = tmp;
    }

    // --- classifier + log_softmax ---
    classifier_bf16<<<(N + 15) / 16, 256, 0, stream>>>(hcur, W_cls, b_cls, outp, N);
}

// Round 10
// 742.813 us; speedup vs baseline: 2.0019x; 1.0089x over previous
//
#include <hip/hip_runtime.h>

typedef unsigned int uint;
typedef unsigned short ushort;
typedef __attribute__((ext_vector_type(8))) short short8v;  // 8 bf16 bit patterns
typedef __attribute__((ext_vector_type(4))) float f32x4;

#define IN_DIM 256
#define HID 128
#define BN_EPS 1e-5f
#define NSHARD 8

__device__ __forceinline__ float bf2f(ushort u) { return __uint_as_float(((uint)u) << 16); }
__device__ __forceinline__ ushort f2bf(float f) {
    uint u = __float_as_uint(f);
    return (ushort)((u + 0x7fffu + ((u >> 16) & 1u)) >> 16);  // RNE
}
// HW packed convert, RNE — 1 op for 2 floats (lo = a, hi = b)
__device__ __forceinline__ uint cvt_pk_bf16(float a, float b) {
    uint r;
    asm("v_cvt_pk_bf16_f32 %0, %1, %2" : "=v"(r) : "v"(a), "v"(b));
    return r;
}

// ---------------- CSR build ----------------

// plain degree count (round-9 sharded variant REGRESSED ~40us: the 8x
// predicated re-scan costs more than the atomic locality saves; sharding
// only pays when it prevents write amplification, i.e. fill_csr).
__global__ void count_deg_kernel(const int* __restrict__ ei, int* __restrict__ deg, int E) {
    int e = blockIdx.x * blockDim.x + threadIdx.x;
    if (e < E) atomicAdd(&deg[ei[E + e]], 1);
}

#define SCAN_THREADS 256
#define SCAN_ELEMS 1024

__global__ __launch_bounds__(SCAN_THREADS) void scan1_kernel(const int* __restrict__ deg,
                                                             int* __restrict__ outp,
                                                             int* __restrict__ bsum, int n) {
    __shared__ int sdata[SCAN_THREADS];
    int t = threadIdx.x;
    int base = blockIdx.x * SCAN_ELEMS + t * 4;
    int v0 = 0, v1 = 0, v2 = 0, v3 = 0;
    if (base + 0 < n) v0 = deg[base + 0];
    if (base + 1 < n) v1 = deg[base + 1];
    if (base + 2 < n) v2 = deg[base + 2];
    if (base + 3 < n) v3 = deg[base + 3];
    int s = v0 + v1 + v2 + v3;
    sdata[t] = s;
    __syncthreads();
    int val = s;
    for (int off = 1; off < SCAN_THREADS; off <<= 1) {
        int add = (t >= off) ? sdata[t - off] : 0;
        __syncthreads();
        val += add;
        sdata[t] = val;
        __syncthreads();
    }
    int excl = val - s;
    if (base + 0 < n) outp[base + 0] = excl;
    if (base + 1 < n) outp[base + 1] = excl + v0;
    if (base + 2 < n) outp[base + 2] = excl + v0 + v1;
    if (base + 3 < n) outp[base + 3] = excl + v0 + v1 + v2;
    if (t == SCAN_THREADS - 1) bsum[blockIdx.x] = val;
}

__global__ void scan2_kernel(int* bsum, int nb) {
    if (threadIdx.x == 0 && blockIdx.x == 0) {
        int acc = 0;
        for (int i = 0; i < nb; i++) { int v = bsum[i]; bsum[i] = acc; acc += v; }
        bsum[nb] = acc;
    }
}

__global__ void scan3_kernel(int* __restrict__ row_ptr, const int* __restrict__ bsum, int n, int nb) {
    int i = blockIdx.x * blockDim.x + threadIdx.x;
    if (i < n) row_ptr[i] += bsum[i >> 10];
    else if (i == n) row_ptr[n] = bsum[nb];
}

// XCD-sharded CSR fill (round-5 WIN: prevents the 102MB masked-line write
// amplification by localizing each esrc slice to one XCD's L2).
__global__ __launch_bounds__(256) void fill_csr_sharded(const int* __restrict__ ei,
                                                        int* __restrict__ cursor,
                                                        int* __restrict__ esrc,
                                                        int E, int shardSize) {
    int s = blockIdx.x & (NSHARD - 1);
    int rank = blockIdx.x >> 3;
    int nteam = gridDim.x >> 3;
    int lo = s * shardSize;
    int hi = lo + shardSize;
    int stride = nteam * blockDim.x;
    for (int e = rank * blockDim.x + threadIdx.x; e < E; e += stride) {
        int d = ei[E + e];
        if (d >= lo && d < hi) {
            int pos = atomicAdd(&cursor[d], 1);
            esrc[pos] = ei[e];
        }
    }
}

// ---------------- Weight pre-pack: fp32 [k][c] -> bf16 [c][k] (frag-ready) ----------------

__global__ __launch_bounds__(256) void pack_win(const float* __restrict__ W, ushort* __restrict__ Wt) {
    int idx = blockIdx.x * 256 + threadIdx.x;
    int k = idx >> 7, c = idx & 127;
    Wt[c * IN_DIM + k] = f2bf(W[idx]);
}

__global__ __launch_bounds__(256) void pack_wcat(const float* __restrict__ Wl,
                                                 const float* __restrict__ Wr,
                                                 ushort* __restrict__ Wt) {
    int idx = blockIdx.x * 256 + threadIdx.x;
    int layer = idx >> 15;
    int rem = idx & 32767;
    int k = rem >> 7, c = rem & 127;
    float v = (k < HID) ? Wl[layer * HID * HID + k * HID + c]
                        : Wr[layer * HID * HID + (k - HID) * HID + c];
    Wt[layer * (HID * 256) + c * 256 + k] = f2bf(v);
}

// ---------------- Aggregation: mean over in-neighbors (bf16 rows) ----------------
// row-gather from L3-resident h; 16 edges in flight (avg degree = 16 ->
// one fully-pipelined batch for most nodes). If this doesn't move vs 8-deep,
// agg is L3-BW-bound, not latency-bound.

__global__ __launch_bounds__(256) void sage_mean_bf16(const ushort* __restrict__ h,
                                                      const int* __restrict__ row_ptr,
                                                      const int* __restrict__ esrc,
                                                      ushort* __restrict__ meanb, int n) {
    int node = blockIdx.x * 4 + (threadIdx.x >> 6);
    if (node >= n) return;
    int lane = threadIdx.x & 63;
    int start = row_ptr[node];
    int end = row_ptr[node + 1];
    float ax = 0.f, ay = 0.f;
    int j = start;
    for (; j + 15 < end; j += 16) {
        uint v[16];
        #pragma unroll
        for (int q = 0; q < 16; q++)
            v[q] = *(const uint*)(h + (size_t)esrc[j + q] * HID + lane * 2);
        #pragma unroll
        for (int q = 0; q < 16; q++) {
            ax += bf2f((ushort)(v[q] & 0xffffu));
            ay += bf2f((ushort)(v[q] >> 16));
        }
    }
    for (; j + 7 < end; j += 8) {
        uint v[8];
        #pragma unroll
        for (int q = 0; q < 8; q++)
            v[q] = *(const uint*)(h + (size_t)esrc[j + q] * HID + lane * 2);
        #pragma unroll
        for (int q = 0; q < 8; q++) {
            ax += bf2f((ushort)(v[q] & 0xffffu));
            ay += bf2f((ushort)(v[q] >> 16));
        }
    }
    for (; j < end; ++j) {
        uint v0 = *(const uint*)(h + (size_t)esrc[j] * HID + lane * 2);
        ax += bf2f((ushort)(v0 & 0xffffu));
        ay += bf2f((ushort)(v0 >> 16));
    }
    int deg = end - start;
    float inv = 1.0f / (float)(deg > 1 ? deg : 1);
    uint o = (uint)f2bf(ax * inv) | (((uint)f2bf(ay * inv)) << 16);
    *(uint*)(meanb + (size_t)node * HID + lane * 2) = o;
}

// ---------------- Input GEMM: h = relu(x @ W_in + b_in), MFMA ----------------
// round 10: 2 M-subtiles (32 rows) per iteration — doubles outstanding
// A-loads & MFMA chains per wave (kernel is latency-bound at 37% occupancy,
// VALUBusy 7%). B-frags 16B loads from packed Wt; A via cvt_pk.

__global__ __launch_bounds__(256) void input_gemm_mfma(const float* __restrict__ x,
                                                       const ushort* __restrict__ Wt,
                                                       const float* __restrict__ b,
                                                       ushort* __restrict__ hout, int n) {
    int t = threadIdx.x;
    int l = t & 63;
    int wv = t >> 6;
    int colbase = wv * 32;
    int lr = l & 15;
    int grp = l >> 4;
    int ko = grp * 8;

    short8v Bf[8][2];
    #pragma unroll
    for (int ks = 0; ks < 8; ks++) {
        #pragma unroll
        for (int nt = 0; nt < 2; nt++) {
            int c = colbase + nt * 16 + lr;
            Bf[ks][nt] = *(const short8v*)(Wt + (size_t)c * IN_DIM + ks * 32 + ko);
        }
    }
    float bias0 = b[colbase + lr];
    float bias1 = b[colbase + 16 + lr];

    int ntiles = (n + 31) >> 5;
    for (int tile = blockIdx.x; tile < ntiles; tile += gridDim.x) {
        int row0 = tile * 32;
        int arow0 = row0 + lr;
        int arow1 = row0 + 16 + lr;
        short8v Af0[8], Af1[8];
        const float* xr0 = x + (size_t)arow0 * IN_DIM + ko;
        const float* xr1 = x + (size_t)arow1 * IN_DIM + ko;
        if (arow0 < n) {
            #pragma unroll
            for (int ks = 0; ks < 8; ks++) {
                float4 p = *(const float4*)(xr0 + ks * 32);
                float4 q = *(const float4*)(xr0 + ks * 32 + 4);
                union { uint4 u; short8v s; } cv;
                cv.u.x = cvt_pk_bf16(p.x, p.y);
                cv.u.y = cvt_pk_bf16(p.z, p.w);
                cv.u.z = cvt_pk_bf16(q.x, q.y);
                cv.u.w = cvt_pk_bf16(q.z, q.w);
                Af0[ks] = cv.s;
            }
        } else {
            #pragma unroll
            for (int ks = 0; ks < 8; ks++) { short8v a = {0,0,0,0,0,0,0,0}; Af0[ks] = a; }
        }
        if (arow1 < n) {
            #pragma unroll
            for (int ks = 0; ks < 8; ks++) {
                float4 p = *(const float4*)(xr1 + ks * 32);
                float4 q = *(const float4*)(xr1 + ks * 32 + 4);
                union { uint4 u; short8v s; } cv;
                cv.u.x = cvt_pk_bf16(p.x, p.y);
                cv.u.y = cvt_pk_bf16(p.z, p.w);
                cv.u.z = cvt_pk_bf16(q.x, q.y);
                cv.u.w = cvt_pk_bf16(q.z, q.w);
                Af1[ks] = cv.s;
            }
        } else {
            #pragma unroll
            for (int ks = 0; ks < 8; ks++) { short8v a = {0,0,0,0,0,0,0,0}; Af1[ks] = a; }
        }
        f32x4 acc00 = {0.f,0.f,0.f,0.f}, acc01 = {0.f,0.f,0.f,0.f};
        f32x4 acc10 = {0.f,0.f,0.f,0.f}, acc11 = {0.f,0.f,0.f,0.f};
        #pragma unroll
        for (int ks = 0; ks < 8; ks++) {
            acc00 = __builtin_amdgcn_mfma_f32_16x16x32_bf16(Af0[ks], Bf[ks][0], acc00, 0, 0, 0);
            acc10 = __builtin_amdgcn_mfma_f32_16x16x32_bf16(Af1[ks], Bf[ks][0], acc10, 0, 0, 0);
            acc01 = __builtin_amdgcn_mfma_f32_16x16x32_bf16(Af0[ks], Bf[ks][1], acc01, 0, 0, 0);
            acc11 = __builtin_amdgcn_mfma_f32_16x16x32_bf16(Af1[ks], Bf[ks][1], acc11, 0, 0, 0);
        }
        int rbase0 = row0 + grp * 4;
        int rbase1 = row0 + 16 + grp * 4;
        #pragma unroll
        for (int r = 0; r < 4; r++) {
            int rowd = rbase0 + r;
            if (rowd < n) {
                float z0 = acc00[r] + bias0; z0 = z0 > 0.f ? z0 : 0.f;
                float z1 = acc01[r] + bias1; z1 = z1 > 0.f ? z1 : 0.f;
                hout[(size_t)rowd * HID + colbase + lr] = f2bf(z0);
                hout[(size_t)rowd * HID + colbase + 16 + lr] = f2bf(z1);
            }
        }
        #pragma unroll
        for (int r = 0; r < 4; r++) {
            int rowd = rbase1 + r;
            if (rowd < n) {
                float z0 = acc10[r] + bias0; z0 = z0 > 0.f ? z0 : 0.f;
                float z1 = acc11[r] + bias1; z1 = z1 > 0.f ? z1 : 0.f;
                hout[(size_t)rowd * HID + colbase + lr] = f2bf(z0);
                hout[(size_t)rowd * HID + colbase + 16 + lr] = f2bf(z1);
            }
        }
    }
}

// ---------------- Fused SAGE layer, MFMA ----------------
// 2 M-subtiles per iteration (same latency rationale). K=256 over concat[mean|h].

__global__ __launch_bounds__(256) void sage_layer_mfma(const ushort* __restrict__ h,
                                                       const ushort* __restrict__ mh,
                                                       ushort* __restrict__ hout,
                                                       const ushort* __restrict__ Wt,
                                                       const float* __restrict__ bl,
                                                       const float* __restrict__ br,
                                                       const float* __restrict__ gamma,
                                                       const float* __restrict__ beta,
                                                       const float* __restrict__ bmean,
                                                       const float* __restrict__ bvar,
                                                       int n) {
    int t = threadIdx.x;
    int l = t & 63;
    int wv = t >> 6;
    int colbase = wv * 32;
    int lr = l & 15;
    int grp = l >> 4;
    int ko = grp * 8;

    short8v Bf[8][2];
    #pragma unroll
    for (int ks = 0; ks < 8; ks++) {
        #pragma unroll
        for (int nt = 0; nt < 2; nt++) {
            int c = colbase + nt * 16 + lr;
            Bf[ks][nt] = *(const short8v*)(Wt + (size_t)c * 256 + ks * 32 + ko);
        }
    }
    int c0 = colbase + lr;
    int c1 = c0 + 16;
    float scale0 = gamma[c0] * rsqrtf(bvar[c0] + BN_EPS);
    float scale1 = gamma[c1] * rsqrtf(bvar[c1] + BN_EPS);
    float shift0 = beta[c0] + (bl[c0] + br[c0] - bmean[c0]) * scale0;
    float shift1 = beta[c1] + (bl[c1] + br[c1] - bmean[c1]) * scale1;

    int ntiles = (n + 31) >> 5;
    for (int tile = blockIdx.x; tile < ntiles; tile += gridDim.x) {
        int row0 = tile * 32;
        int arow0 = row0 + lr;
        int arow1 = row0 + 16 + lr;
        short8v Af0[8], Af1[8];
        if (arow0 < n) {
            const ushort* mrow = mh + (size_t)arow0 * HID + ko;
            const ushort* hrow = h + (size_t)arow0 * HID + ko;
            #pragma unroll
            for (int ks = 0; ks < 4; ks++) Af0[ks] = *(const short8v*)(mrow + ks * 32);
            #pragma unroll
            for (int ks = 4; ks < 8; ks++) Af0[ks] = *(const short8v*)(hrow + (ks - 4) * 32);
        } else {
            #pragma unroll
            for (int ks = 0; ks < 8; ks++) { short8v a = {0,0,0,0,0,0,0,0}; Af0[ks] = a; }
        }
        if (arow1 < n) {
            const ushort* mrow = mh + (size_t)arow1 * HID + ko;
            const ushort* hrow = h + (size_t)arow1 * HID + ko;
            #pragma unroll
            for (int ks = 0; ks < 4; ks++) Af1[ks] = *(const short8v*)(mrow + ks * 32);
            #pragma unroll
            for (int ks = 4; ks < 8; ks++) Af1[ks] = *(const short8v*)(hrow + (ks - 4) * 32);
        } else {
            #pragma unroll
            for (int ks = 0; ks < 8; ks++) { short8v a = {0,0,0,0,0,0,0,0}; Af1[ks] = a; }
        }
        f32x4 acc00 = {0.f,0.f,0.f,0.f}, acc01 = {0.f,0.f,0.f,0.f};
        f32x4 acc10 = {0.f,0.f,0.f,0.f}, acc11 = {0.f,0.f,0.f,0.f};
        #pragma unroll
        for (int ks = 0; ks < 8; ks++) {
            acc00 = __builtin_amdgcn_mfma_f32_16x16x32_bf16(Af0[ks], Bf[ks][0], acc00, 0, 0, 0);
            acc10 = __builtin_amdgcn_mfma_f32_16x16x32_bf16(Af1[ks], Bf[ks][0], acc10, 0, 0, 0);
            acc01 = __builtin_amdgcn_mfma_f32_16x16x32_bf16(Af0[ks], Bf[ks][1], acc01, 0, 0, 0);
            acc11 = __builtin_amdgcn_mfma_f32_16x16x32_bf16(Af1[ks], Bf[ks][1], acc11, 0, 0, 0);
        }
        int rbase0 = row0 + grp * 4;
        int rbase1 = row0 + 16 + grp * 4;
        #pragma unroll
        for (int r = 0; r < 4; r++) {
            int rowd = rbase0 + r;
            if (rowd < n) {
                float z0 = acc00[r] * scale0 + shift0; z0 = z0 > 0.f ? z0 : 0.f;
                float z1 = acc01[r] * scale1 + shift1; z1 = z1 > 0.f ? z1 : 0.f;
                z0 += bf2f(h[(size_t)rowd * HID + c0]);
                z1 += bf2f(h[(size_t)rowd * HID + c1]);
                hout[(size_t)rowd * HID + c0] = f2bf(z0);
                hout[(size_t)rowd * HID + c1] = f2bf(z1);
            }
        }
        #pragma unroll
        for (int r = 0; r < 4; r++) {
            int rowd = rbase1 + r;
            if (rowd < n) {
                float z0 = acc10[r] * scale0 + shift0; z0 = z0 > 0.f ? z0 : 0.f;
                float z1 = acc11[r] * scale1 + shift1; z1 = z1 > 0.f ? z1 : 0.f;
                z0 += bf2f(h[(size_t)rowd * HID + c0]);
                z1 += bf2f(h[(size_t)rowd * HID + c1]);
                hout[(size_t)rowd * HID + c0] = f2bf(z0);
                hout[(size_t)rowd * HID + c1] = f2bf(z1);
            }
        }
    }
}

// ---------------- Classifier + log_softmax (bf16 h) ----------------

__global__ __launch_bounds__(256) void classifier_bf16(const ushort* __restrict__ h,
                                                       const float* __restrict__ Wc,
                                                       const float* __restrict__ bc,
                                                       float* __restrict__ outp, int n) {
    __shared__ float Wcs[HID * 2];
    int t = threadIdx.x;
    if (t < 64) *(float4*)&Wcs[t * 4] = *(const float4*)&Wc[t * 4];
    __syncthreads();
    int rowInBlk = t >> 4;
    int sub = t & 15;
    int row = blockIdx.x * 16 + rowInBlk;
    float l0 = 0.f, l1 = 0.f;
    if (row < n) {
        const ushort* hr = h + (size_t)row * HID + sub * 8;
        uint4 v = *(const uint4*)hr;
        float e0 = bf2f((ushort)(v.x & 0xffffu)), e1 = bf2f((ushort)(v.x >> 16));
        float e2 = bf2f((ushort)(v.y & 0xffffu)), e3 = bf2f((ushort)(v.y >> 16));
        float e4 = bf2f((ushort)(v.z & 0xffffu)), e5 = bf2f((ushort)(v.z >> 16));
        float e6 = bf2f((ushort)(v.w & 0xffffu)), e7 = bf2f((ushort)(v.w >> 16));
        int k0 = sub * 8;
        l0 += e0 * Wcs[(k0 + 0) * 2] + e1 * Wcs[(k0 + 1) * 2] + e2 * Wcs[(k0 + 2) * 2] + e3 * Wcs[(k0 + 3) * 2];
        l0 += e4 * Wcs[(k0 + 4) * 2] + e5 * Wcs[(k0 + 5) * 2] + e6 * Wcs[(k0 + 6) * 2] + e7 * Wcs[(k0 + 7) * 2];
        l1 += e0 * Wcs[(k0 + 0) * 2 + 1] + e1 * Wcs[(k0 + 1) * 2 + 1] + e2 * Wcs[(k0 + 2) * 2 + 1] + e3 * Wcs[(k0 + 3) * 2 + 1];
        l1 += e4 * Wcs[(k0 + 4) * 2 + 1] + e5 * Wcs[(k0 + 5) * 2 + 1] + e6 * Wcs[(k0 + 6) * 2 + 1] + e7 * Wcs[(k0 + 7) * 2 + 1];
    }
    #pragma unroll
    for (int off = 1; off < 16; off <<= 1) {
        l0 += __shfl_xor(l0, off);
        l1 += __shfl_xor(l1, off);
    }
    if (sub == 0 && row < n) {
        l0 += bc[0];
        l1 += bc[1];
        float m = fmaxf(l0, l1);
        float lse = m + logf(expf(l0 - m) + expf(l1 - m));
        outp[(size_t)row * 2 + 0] = l0 - lse;
        outp[(size_t)row * 2 + 1] = l1 - lse;
    }
}

// ---------------- host ----------------

extern "C" void kernel_launch(void* const* d_in, const int* in_sizes, int n_in,
                              void* d_out, int out_size, void* d_ws, size_t ws_size,
                              hipStream_t stream) {
    const float* x     = (const float*)d_in[0];
    const int*   ei    = (const int*)d_in[1];
    const float* W_in  = (const float*)d_in[2];
    const float* b_in  = (const float*)d_in[3];
    const float* W_l   = (const float*)d_in[4];
    const float* b_l   = (const float*)d_in[5];
    const float* W_r   = (const float*)d_in[6];
    const float* b_r   = (const float*)d_in[7];
    const float* bn_g  = (const float*)d_in[8];
    const float* bn_b  = (const float*)d_in[9];
    const float* bn_m  = (const float*)d_in[10];
    const float* bn_v  = (const float*)d_in[11];
    const float* W_cls = (const float*)d_in[12];
    const float* b_cls = (const float*)d_in[13];
    float* outp = (float*)d_out;

    const int N = in_sizes[0] / IN_DIM;   // 100000
    const int E = in_sizes[1] / 2;        // 1600000

    char* w = (char*)d_ws;
    const size_t HB = (size_t)N * HID * sizeof(ushort);          // 25.6 MB per buffer
    ushort* hA     = (ushort*)(w);
    ushort* hB     = (ushort*)(w + HB);
    ushort* meanb  = (ushort*)(w + 2 * HB);
    ushort* Wt_in  = (ushort*)(w + 3 * HB);                      // 64 KB
    ushort* WcatT  = (ushort*)(w + 3 * HB + 65536);              // 256 KB
    char*  ints    = w + 3 * HB + 65536 + 262144;
    int*   row_ptr = (int*)(ints);                               // N+1 ints
    int*   cursor  = (int*)(ints + 400128);
    int*   bsum    = (int*)(ints + 800256);
    int*   esrc    = (int*)(ints + 801280);                      // E ints

    const int nbScan = (N + SCAN_ELEMS - 1) / SCAN_ELEMS;
    const int shardSize = (N + NSHARD - 1) / NSHARD;             // 12500

    // --- weight pre-pack (bf16, frag-ready [c][k]) ---
    pack_win<<<128, 256, 0, stream>>>(W_in, Wt_in);
    pack_wcat<<<512, 256, 0, stream>>>(W_l, W_r, WcatT);

    // --- CSR build ---
    hipMemsetAsync(cursor, 0, (size_t)N * sizeof(int), stream);
    count_deg_kernel<<<(E + 255) / 256, 256, 0, stream>>>(ei, cursor, E);
    scan1_kernel<<<nbScan, SCAN_THREADS, 0, stream>>>(cursor, row_ptr, bsum, N);
    scan2_kernel<<<1, 64, 0, stream>>>(bsum, nbScan);
    scan3_kernel<<<(N + 256) / 256, 256, 0, stream>>>(row_ptr, bsum, N, nbScan);
    hipMemcpyAsync(cursor, row_ptr, (size_t)N * sizeof(int), hipMemcpyDeviceToDevice, stream);
    fill_csr_sharded<<<2048, 256, 0, stream>>>(ei, cursor, esrc, E, shardSize);

    // --- input projection (fp32 x -> bf16 h) ---
    input_gemm_mfma<<<3125, 256, 0, stream>>>(x, Wt_in, b_in, hA, N);   // 3125 x 32-row tiles

    // --- 4 SAGE layers ---
    ushort* hcur = hA;
    ushort* hoth = hB;
    for (int i = 0; i < 4; i++) {
        sage_mean_bf16<<<(N + 3) / 4, 256, 0, stream>>>(hcur, row_ptr, esrc, meanb, N);
        sage_layer_mfma<<<3125, 256, 0, stream>>>(hcur, meanb, hoth,
                                                  WcatT + (size_t)i * HID * 256,
                                                  b_l + i * HID, b_r + i * HID,
                                                  bn_g + i * HID, bn_b + i * HID,
                                                  bn_m + i * HID, bn_v + i * HID, N);
        ushort* tmp = hcur; hcur = hoth; hoth = tmp;
    }

    // --- classifier + log_softmax ---
    classifier_bf16<<<(N + 15) / 16, 256, 0, stream>>>(hcur, W_cls, b_cls, outp, N);
}

// Round 11
// 580.385 us; speedup vs baseline: 2.5622x; 1.2799x over previous
//
#include <hip/hip_runtime.h>

typedef unsigned int uint;
typedef unsigned short ushort;
typedef __attribute__((ext_vector_type(8))) short short8v;  // 8 bf16 bit patterns
typedef __attribute__((ext_vector_type(4))) float f32x4;

#define IN_DIM 256
#define HID 128
#define BN_EPS 1e-5f
#define NSHARD 8

__device__ __forceinline__ float bf2f(ushort u) { return __uint_as_float(((uint)u) << 16); }
__device__ __forceinline__ ushort f2bf(float f) {
    uint u = __float_as_uint(f);
    return (ushort)((u + 0x7fffu + ((u >> 16) & 1u)) >> 16);  // RNE
}
__device__ __forceinline__ uint cvt_pk_bf16(float a, float b) {
    uint r;
    asm("v_cvt_pk_bf16_f32 %0, %1, %2" : "=v"(r) : "v"(a), "v"(b));
    return r;
}
// async global->LDS, 16B/lane. LDS dest = wave-uniform base + lane*16;
// global src is PER-LANE (guide: pre-swizzled-source pattern, m173).
__device__ __forceinline__ void gload_lds16(const void* g, void* l) {
    __builtin_amdgcn_global_load_lds(
        (const __attribute__((address_space(1))) uint*)g,
        (__attribute__((address_space(3))) uint*)l, 16, 0, 0);
}

// ---------------- CSR build ----------------

__global__ void count_deg_kernel(const int* __restrict__ ei, int* __restrict__ deg, int E) {
    int e = blockIdx.x * blockDim.x + threadIdx.x;
    if (e < E) atomicAdd(&deg[ei[E + e]], 1);
}

#define SCAN_THREADS 256
#define SCAN_ELEMS 1024

__global__ __launch_bounds__(SCAN_THREADS) void scan1_kernel(const int* __restrict__ deg,
                                                             int* __restrict__ outp,
                                                             int* __restrict__ bsum, int n) {
    __shared__ int sdata[SCAN_THREADS];
    int t = threadIdx.x;
    int base = blockIdx.x * SCAN_ELEMS + t * 4;
    int v0 = 0, v1 = 0, v2 = 0, v3 = 0;
    if (base + 0 < n) v0 = deg[base + 0];
    if (base + 1 < n) v1 = deg[base + 1];
    if (base + 2 < n) v2 = deg[base + 2];
    if (base + 3 < n) v3 = deg[base + 3];
    int s = v0 + v1 + v2 + v3;
    sdata[t] = s;
    __syncthreads();
    int val = s;
    for (int off = 1; off < SCAN_THREADS; off <<= 1) {
        int add = (t >= off) ? sdata[t - off] : 0;
        __syncthreads();
        val += add;
        sdata[t] = val;
        __syncthreads();
    }
    int excl = val - s;
    if (base + 0 < n) outp[base + 0] = excl;
    if (base + 1 < n) outp[base + 1] = excl + v0;
    if (base + 2 < n) outp[base + 2] = excl + v0 + v1;
    if (base + 3 < n) outp[base + 3] = excl + v0 + v1 + v2;
    if (t == SCAN_THREADS - 1) bsum[blockIdx.x] = val;
}

__global__ void scan2_kernel(int* bsum, int nb) {
    if (threadIdx.x == 0 && blockIdx.x == 0) {
        int acc = 0;
        for (int i = 0; i < nb; i++) { int v = bsum[i]; bsum[i] = acc; acc += v; }
        bsum[nb] = acc;
    }
}

__global__ void scan3_kernel(int* __restrict__ row_ptr, const int* __restrict__ bsum, int n, int nb) {
    int i = blockIdx.x * blockDim.x + threadIdx.x;
    if (i < n) row_ptr[i] += bsum[i >> 10];
    else if (i == n) row_ptr[n] = bsum[nb];
}

// XCD-sharded CSR fill (round-5 WIN: prevents masked-line write amplification).
__global__ __launch_bounds__(256) void fill_csr_sharded(const int* __restrict__ ei,
                                                        int* __restrict__ cursor,
                                                        int* __restrict__ esrc,
                                                        int E, int shardSize) {
    int s = blockIdx.x & (NSHARD - 1);
    int rank = blockIdx.x >> 3;
    int nteam = gridDim.x >> 3;
    int lo = s * shardSize;
    int hi = lo + shardSize;
    int stride = nteam * blockDim.x;
    for (int e = rank * blockDim.x + threadIdx.x; e < E; e += stride) {
        int d = ei[E + e];
        if (d >= lo && d < hi) {
            int pos = atomicAdd(&cursor[d], 1);
            esrc[pos] = ei[e];
        }
    }
}

// ---------------- Weight pre-pack: fp32 [k][c] -> bf16 [c][k] (frag-ready) ----------------

__global__ __launch_bounds__(256) void pack_win(const float* __restrict__ W, ushort* __restrict__ Wt) {
    int idx = blockIdx.x * 256 + threadIdx.x;
    int k = idx >> 7, c = idx & 127;
    Wt[c * IN_DIM + k] = f2bf(W[idx]);
}

__global__ __launch_bounds__(256) void pack_wcat(const float* __restrict__ Wl,
                                                 const float* __restrict__ Wr,
                                                 ushort* __restrict__ Wt) {
    int idx = blockIdx.x * 256 + threadIdx.x;
    int layer = idx >> 15;
    int rem = idx & 32767;
    int k = rem >> 7, c = rem & 127;
    float v = (k < HID) ? Wl[layer * HID * HID + k * HID + c]
                        : Wr[layer * HID * HID + (k - HID) * HID + c];
    Wt[layer * (HID * 256) + c * 256 + k] = f2bf(v);
}

// ---------------- Aggregation: mean over in-neighbors (bf16 rows) ----------------

__global__ __launch_bounds__(256) void sage_mean_bf16(const ushort* __restrict__ h,
                                                      const int* __restrict__ row_ptr,
                                                      const int* __restrict__ esrc,
                                                      ushort* __restrict__ meanb, int n) {
    int node = blockIdx.x * 4 + (threadIdx.x >> 6);
    if (node >= n) return;
    int lane = threadIdx.x & 63;
    int start = row_ptr[node];
    int end = row_ptr[node + 1];
    float ax = 0.f, ay = 0.f;
    int j = start;
    for (; j + 15 < end; j += 16) {
        uint v[16];
        #pragma unroll
        for (int q = 0; q < 16; q++)
            v[q] = *(const uint*)(h + (size_t)esrc[j + q] * HID + lane * 2);
        #pragma unroll
        for (int q = 0; q < 16; q++) {
            ax += bf2f((ushort)(v[q] & 0xffffu));
            ay += bf2f((ushort)(v[q] >> 16));
        }
    }
    for (; j + 7 < end; j += 8) {
        uint v[8];
        #pragma unroll
        for (int q = 0; q < 8; q++)
            v[q] = *(const uint*)(h + (size_t)esrc[j + q] * HID + lane * 2);
        #pragma unroll
        for (int q = 0; q < 8; q++) {
            ax += bf2f((ushort)(v[q] & 0xffffu));
            ay += bf2f((ushort)(v[q] >> 16));
        }
    }
    for (; j < end; ++j) {
        uint v0 = *(const uint*)(h + (size_t)esrc[j] * HID + lane * 2);
        ax += bf2f((ushort)(v0 & 0xffffu));
        ay += bf2f((ushort)(v0 >> 16));
    }
    int deg = end - start;
    float inv = 1.0f / (float)(deg > 1 ? deg : 1);
    uint o = (uint)f2bf(ax * inv) | (((uint)f2bf(ay * inv)) << 16);
    *(uint*)(meanb + (size_t)node * HID + lane * 2) = o;
}

// ---------------- Input GEMM: h = relu(x @ W_in + b_in), MFMA ----------------
// round 11: A-tile (32 rows x 256 fp32 = 32KB) staged ONCE per block via
// global_load_lds (coalesced, pre-swizzled source), shared by all 4 waves
// (kills the 4x A duplication + 64-piece scattered loads that made rounds
// 5-10 issue-bound at 1.2TB/s). XOR swizzle byte^=((row&7)<<4) on both
// stage-source and ds_read (involution; banks balanced).

__global__ __launch_bounds__(256) void input_gemm_mfma(const float* __restrict__ x,
                                                       const ushort* __restrict__ Wt,
                                                       const float* __restrict__ b,
                                                       ushort* __restrict__ hout, int n) {
    __shared__ float Axs[32 * IN_DIM];  // 32KB
    int t = threadIdx.x;
    int l = t & 63;
    int wv = t >> 6;
    int colbase = wv * 32;
    int lr = l & 15;
    int grp = l >> 4;
    int ko = grp * 8;

    short8v Bf[8][2];
    #pragma unroll
    for (int ks = 0; ks < 8; ks++) {
        #pragma unroll
        for (int nt = 0; nt < 2; nt++) {
            int c = colbase + nt * 16 + lr;
            Bf[ks][nt] = *(const short8v*)(Wt + (size_t)c * IN_DIM + ks * 32 + ko);
        }
    }
    float bias0 = b[colbase + lr];
    float bias1 = b[colbase + 16 + lr];

    int ntiles = (n + 31) >> 5;   // N=100000 -> 3125 tiles exactly
    for (int tile = blockIdx.x; tile < ntiles; tile += gridDim.x) {
        int row0 = tile * 32;
        __syncthreads();  // protect LDS reuse across grid-stride iterations
        // stage 32KB: 8 wave-instrs; per-lane SOURCE pre-swizzled, LDS linear
        {
            const char* xb = (const char*)(x + (size_t)row0 * IN_DIM);
            char* lb = (char*)Axs;
            #pragma unroll
            for (int i = 0; i < 8; i++) {
                int off = i * 4096 + t * 16;
                int src = off ^ (((off >> 10) & 7) << 4);
                gload_lds16(xb + src, lb + i * 4096 + wv * 1024);
            }
        }
        __syncthreads();
        f32x4 acc00 = {0.f,0.f,0.f,0.f}, acc01 = {0.f,0.f,0.f,0.f};
        f32x4 acc10 = {0.f,0.f,0.f,0.f}, acc11 = {0.f,0.f,0.f,0.f};
        #pragma unroll
        for (int m = 0; m < 2; m++) {
            int r = m * 16 + lr;
            int rswz = (r & 7) << 4;
            const char* rowp = (const char*)Axs + r * 1024;
            short8v Af[8];
            #pragma unroll
            for (int ks = 0; ks < 8; ks++) {
                int kb = (ko + ks * 32) * 4;
                float4 p = *(const float4*)(rowp + (kb ^ rswz));
                float4 q = *(const float4*)(rowp + ((kb + 16) ^ rswz));
                union { uint4 u; short8v s; } cv;
                cv.u.x = cvt_pk_bf16(p.x, p.y);
                cv.u.y = cvt_pk_bf16(p.z, p.w);
                cv.u.z = cvt_pk_bf16(q.x, q.y);
                cv.u.w = cvt_pk_bf16(q.z, q.w);
                Af[ks] = cv.s;
            }
            if (m == 0) {
                #pragma unroll
                for (int ks = 0; ks < 8; ks++) {
                    acc00 = __builtin_amdgcn_mfma_f32_16x16x32_bf16(Af[ks], Bf[ks][0], acc00, 0, 0, 0);
                    acc01 = __builtin_amdgcn_mfma_f32_16x16x32_bf16(Af[ks], Bf[ks][1], acc01, 0, 0, 0);
                }
            } else {
                #pragma unroll
                for (int ks = 0; ks < 8; ks++) {
                    acc10 = __builtin_amdgcn_mfma_f32_16x16x32_bf16(Af[ks], Bf[ks][0], acc10, 0, 0, 0);
                    acc11 = __builtin_amdgcn_mfma_f32_16x16x32_bf16(Af[ks], Bf[ks][1], acc11, 0, 0, 0);
                }
            }
        }
        #pragma unroll
        for (int m = 0; m < 2; m++) {
            int rbase = row0 + m * 16 + grp * 4;
            f32x4 a0 = m == 0 ? acc00 : acc10;
            f32x4 a1 = m == 0 ? acc01 : acc11;
            #pragma unroll
            for (int r = 0; r < 4; r++) {
                int rowd = rbase + r;
                if (rowd < n) {
                    float z0 = a0[r] + bias0; z0 = z0 > 0.f ? z0 : 0.f;
                    float z1 = a1[r] + bias1; z1 = z1 > 0.f ? z1 : 0.f;
                    hout[(size_t)rowd * HID + colbase + lr] = f2bf(z0);
                    hout[(size_t)rowd * HID + colbase + 16 + lr] = f2bf(z1);
                }
            }
        }
    }
}

// ---------------- Fused SAGE layer, MFMA ----------------
// round 11: tile 64 rows x 128 cols; Ams/Ahs (16KB each) staged via
// global_load_lds + XOR swizzle, shared by 4 waves (each wave: 4 M-subtiles
// x its 32 cols). Residual h[rowd][c] read from Ahs (free). B in regs.
// OOB staging rows on the last tile read adjacent ws buffers (safe, masked).

__global__ __launch_bounds__(256) void sage_layer_mfma(const ushort* __restrict__ h,
                                                       const ushort* __restrict__ mh,
                                                       ushort* __restrict__ hout,
                                                       const ushort* __restrict__ Wt,
                                                       const float* __restrict__ bl,
                                                       const float* __restrict__ br,
                                                       const float* __restrict__ gamma,
                                                       const float* __restrict__ beta,
                                                       const float* __restrict__ bmean,
                                                       const float* __restrict__ bvar,
                                                       int n) {
    __shared__ ushort Ams[64 * HID];  // 16KB (mean rows)
    __shared__ ushort Ahs[64 * HID];  // 16KB (h rows)
    int t = threadIdx.x;
    int l = t & 63;
    int wv = t >> 6;
    int colbase = wv * 32;
    int lr = l & 15;
    int grp = l >> 4;
    int ko = grp * 8;

    short8v Bf[8][2];
    #pragma unroll
    for (int ks = 0; ks < 8; ks++) {
        #pragma unroll
        for (int nt = 0; nt < 2; nt++) {
            int c = colbase + nt * 16 + lr;
            Bf[ks][nt] = *(const short8v*)(Wt + (size_t)c * 256 + ks * 32 + ko);
        }
    }
    int c0 = colbase + lr;
    int c1 = c0 + 16;
    float scale0 = gamma[c0] * rsqrtf(bvar[c0] + BN_EPS);
    float scale1 = gamma[c1] * rsqrtf(bvar[c1] + BN_EPS);
    float shift0 = beta[c0] + (bl[c0] + br[c0] - bmean[c0]) * scale0;
    float shift1 = beta[c1] + (bl[c1] + br[c1] - bmean[c1]) * scale1;

    int ntiles = (n + 63) >> 6;
    for (int tile = blockIdx.x; tile < ntiles; tile += gridDim.x) {
        int row0 = tile * 64;
        __syncthreads();
        {
            const char* mb = (const char*)(mh + (size_t)row0 * HID);
            const char* hb = (const char*)(h + (size_t)row0 * HID);
            char* lm = (char*)Ams;
            char* lh = (char*)Ahs;
            #pragma unroll
            for (int i = 0; i < 4; i++) {
                int off = i * 4096 + t * 16;
                int src = off ^ (((off >> 8) & 7) << 4);
                gload_lds16(mb + src, lm + i * 4096 + wv * 1024);
                gload_lds16(hb + src, lh + i * 4096 + wv * 1024);
            }
        }
        __syncthreads();
        #pragma unroll
        for (int m = 0; m < 4; m++) {
            int r = m * 16 + lr;
            int rswz = (r & 7) << 4;
            const char* mrow = (const char*)Ams + r * 256;
            const char* hrow = (const char*)Ahs + r * 256;
            short8v Af[8];
            #pragma unroll
            for (int ks = 0; ks < 4; ks++) {
                int kb = (ko + ks * 32) * 2;
                Af[ks] = *(const short8v*)(mrow + (kb ^ rswz));
            }
            #pragma unroll
            for (int ks = 4; ks < 8; ks++) {
                int kb = (ko + (ks - 4) * 32) * 2;
                Af[ks] = *(const short8v*)(hrow + (kb ^ rswz));
            }
            f32x4 acc0 = {0.f,0.f,0.f,0.f};
            f32x4 acc1 = {0.f,0.f,0.f,0.f};
            #pragma unroll
            for (int ks = 0; ks < 8; ks++) {
                acc0 = __builtin_amdgcn_mfma_f32_16x16x32_bf16(Af[ks], Bf[ks][0], acc0, 0, 0, 0);
                acc1 = __builtin_amdgcn_mfma_f32_16x16x32_bf16(Af[ks], Bf[ks][1], acc1, 0, 0, 0);
            }
            int rbase = m * 16 + grp * 4;
            #pragma unroll
            for (int r2 = 0; r2 < 4; r2++) {
                int rloc = rbase + r2;
                int rowd = row0 + rloc;
                if (rowd < n) {
                    int rs = (rloc & 7) << 4;
                    float res0 = bf2f(*(const ushort*)((const char*)Ahs + rloc * 256 + ((c0 * 2) ^ rs)));
                    float res1 = bf2f(*(const ushort*)((const char*)Ahs + rloc * 256 + ((c1 * 2) ^ rs)));
                    float z0 = acc0[r2] * scale0 + shift0; z0 = z0 > 0.f ? z0 : 0.f;
                    float z1 = acc1[r2] * scale1 + shift1; z1 = z1 > 0.f ? z1 : 0.f;
                    hout[(size_t)rowd * HID + c0] = f2bf(z0 + res0);
                    hout[(size_t)rowd * HID + c1] = f2bf(z1 + res1);
                }
            }
        }
    }
}

// ---------------- Classifier + log_softmax (bf16 h) ----------------

__global__ __launch_bounds__(256) void classifier_bf16(const ushort* __restrict__ h,
                                                       const float* __restrict__ Wc,
                                                       const float* __restrict__ bc,
                                                       float* __restrict__ outp, int n) {
    __shared__ float Wcs[HID * 2];
    int t = threadIdx.x;
    if (t < 64) *(float4*)&Wcs[t * 4] = *(const float4*)&Wc[t * 4];
    __syncthreads();
    int rowInBlk = t >> 4;
    int sub = t & 15;
    int row = blockIdx.x * 16 + rowInBlk;
    float l0 = 0.f, l1 = 0.f;
    if (row < n) {
        const ushort* hr = h + (size_t)row * HID + sub * 8;
        uint4 v = *(const uint4*)hr;
        float e0 = bf2f((ushort)(v.x & 0xffffu)), e1 = bf2f((ushort)(v.x >> 16));
        float e2 = bf2f((ushort)(v.y & 0xffffu)), e3 = bf2f((ushort)(v.y >> 16));
        float e4 = bf2f((ushort)(v.z & 0xffffu)), e5 = bf2f((ushort)(v.z >> 16));
        float e6 = bf2f((ushort)(v.w & 0xffffu)), e7 = bf2f((ushort)(v.w >> 16));
        int k0 = sub * 8;
        l0 += e0 * Wcs[(k0 + 0) * 2] + e1 * Wcs[(k0 + 1) * 2] + e2 * Wcs[(k0 + 2) * 2] + e3 * Wcs[(k0 + 3) * 2];
        l0 += e4 * Wcs[(k0 + 4) * 2] + e5 * Wcs[(k0 + 5) * 2] + e6 * Wcs[(k0 + 6) * 2] + e7 * Wcs[(k0 + 7) * 2];
        l1 += e0 * Wcs[(k0 + 0) * 2 + 1] + e1 * Wcs[(k0 + 1) * 2 + 1] + e2 * Wcs[(k0 + 2) * 2 + 1] + e3 * Wcs[(k0 + 3) * 2 + 1];
        l1 += e4 * Wcs[(k0 + 4) * 2 + 1] + e5 * Wcs[(k0 + 5) * 2 + 1] + e6 * Wcs[(k0 + 6) * 2 + 1] + e7 * Wcs[(k0 + 7) * 2 + 1];
    }
    #pragma unroll
    for (int off = 1; off < 16; off <<= 1) {
        l0 += __shfl_xor(l0, off);
        l1 += __shfl_xor(l1, off);
    }
    if (sub == 0 && row < n) {
        l0 += bc[0];
        l1 += bc[1];
        float m = fmaxf(l0, l1);
        float lse = m + logf(expf(l0 - m) + expf(l1 - m));
        outp[(size_t)row * 2 + 0] = l0 - lse;
        outp[(size_t)row * 2 + 1] = l1 - lse;
    }
}

// ---------------- host ----------------

extern "C" void kernel_launch(void* const* d_in, const int* in_sizes, int n_in,
                              void* d_out, int out_size, void* d_ws, size_t ws_size,
                              hipStream_t stream) {
    const float* x     = (const float*)d_in[0];
    const int*   ei    = (const int*)d_in[1];
    const float* W_in  = (const float*)d_in[2];
    const float* b_in  = (const float*)d_in[3];
    const float* W_l   = (const float*)d_in[4];
    const float* b_l   = (const float*)d_in[5];
    const float* W_r   = (const float*)d_in[6];
    const float* b_r   = (const float*)d_in[7];
    const float* bn_g  = (const float*)d_in[8];
    const float* bn_b  = (const float*)d_in[9];
    const float* bn_m  = (const float*)d_in[10];
    const float* bn_v  = (const float*)d_in[11];
    const float* W_cls = (const float*)d_in[12];
    const float* b_cls = (const float*)d_in[13];
    float* outp = (float*)d_out;

    const int N = in_sizes[0] / IN_DIM;   // 100000
    const int E = in_sizes[1] / 2;        // 1600000

    char* w = (char*)d_ws;
    const size_t HB = (size_t)N * HID * sizeof(ushort);          // 25.6 MB per buffer
    ushort* hA     = (ushort*)(w);
    ushort* hB     = (ushort*)(w + HB);
    ushort* meanb  = (ushort*)(w + 2 * HB);
    ushort* Wt_in  = (ushort*)(w + 3 * HB);                      // 64 KB
    ushort* WcatT  = (ushort*)(w + 3 * HB + 65536);              // 256 KB
    char*  ints    = w + 3 * HB + 65536 + 262144;
    int*   row_ptr = (int*)(ints);                               // N+1 ints
    int*   cursor  = (int*)(ints + 400128);
    int*   bsum    = (int*)(ints + 800256);
    int*   esrc    = (int*)(ints + 801280);                      // E ints

    const int nbScan = (N + SCAN_ELEMS - 1) / SCAN_ELEMS;
    const int shardSize = (N + NSHARD - 1) / NSHARD;             // 12500

    // --- weight pre-pack (bf16, frag-ready [c][k]) ---
    pack_win<<<128, 256, 0, stream>>>(W_in, Wt_in);
    pack_wcat<<<512, 256, 0, stream>>>(W_l, W_r, WcatT);

    // --- CSR build ---
    hipMemsetAsync(cursor, 0, (size_t)N * sizeof(int), stream);
    count_deg_kernel<<<(E + 255) / 256, 256, 0, stream>>>(ei, cursor, E);
    scan1_kernel<<<nbScan, SCAN_THREADS, 0, stream>>>(cursor, row_ptr, bsum, N);
    scan2_kernel<<<1, 64, 0, stream>>>(bsum, nbScan);
    scan3_kernel<<<(N + 256) / 256, 256, 0, stream>>>(row_ptr, bsum, N, nbScan);
    hipMemcpyAsync(cursor, row_ptr, (size_t)N * sizeof(int), hipMemcpyDeviceToDevice, stream);
    fill_csr_sharded<<<2048, 256, 0, stream>>>(ei, cursor, esrc, E, shardSize);

    // --- input projection (fp32 x -> bf16 h) ---
    input_gemm_mfma<<<(N + 31) / 32, 256, 0, stream>>>(x, Wt_in, b_in, hA, N);

    // --- 4 SAGE layers ---
    ushort* hcur = hA;
    ushort* hoth = hB;
    for (int i = 0; i < 4; i++) {
        sage_mean_bf16<<<(N + 3) / 4, 256, 0, stream>>>(hcur, row_ptr, esrc, meanb, N);
        sage_layer_mfma<<<(N + 63) / 64, 256, 0, stream>>>(hcur, meanb, hoth,
                                                  WcatT + (size_t)i * HID * 256,
                                                  b_l + i * HID, b_r + i * HID,
                                                  bn_g + i * HID, bn_b + i * HID,
                                                  bn_m + i * HID, bn_v + i * HID, N);
        ushort* tmp = hcur; hcur = hoth; hoth = tmp;
    }

    // --- classifier + log_softmax ---
    classifier_bf16<<<(N + 15) / 16, 256, 0, stream>>>(hcur, W_cls, b_cls, outp, N);
}